// Round 2
// baseline (2124.992 us; speedup 1.0000x reference)
//
#include <hip/hip_runtime.h>
#include <math.h>

// MoE gate, fused, fp64-exact ranking:
//   fp64-accumulated gating GEMM + fp64 sigmoid/bias + grouped top-2 sums +
//   top-4 groups + masked top-8 + normalized weights.
//
// T=16384, H=7168, E=256, 8 groups of 32, top4 groups, top8 experts.
// Output (float*): [0 .. T*8) = topk_idx as float, [T*8 .. 2*T*8) = topk_weight.

constexpr int T_TOT  = 16384;
constexpr int HID    = 7168;
constexpr int NEXP   = 256;
constexpr int BM     = 32;           // tokens per block
constexpr int BK     = 32;           // K-chunk
constexpr int NCHUNK = HID / BK;     // 224
constexpr int XSTR   = 40;           // padded stride of x tile (breaks wr-bank conflicts)

__global__ __launch_bounds__(256)
void moe_gate_fp64(const float* __restrict__ x,
                   const float* __restrict__ w,
                   const float* __restrict__ bias,
                   float* __restrict__ out)
{
    __shared__ __align__(16) float lds_w[BK * NEXP];  // ws(k,e) = lds_w[k*256 + e]
    __shared__ __align__(16) float lds_x[BK * XSTR];  // xs(k,m) = lds_x[k*40 + m]

    const int tid   = threadIdx.x;
    const long trow0 = (long)blockIdx.x * BM;

    // compute mapping: half-wave (32 lanes) owns 4 tokens x all 256 experts.
    // lane l owns experts [4l..4l+3] and [128+4l..128+4l+3] (two contiguous quads
    // -> ds_read_b128 across lanes is fully linear, conflict-free).
    const int tg  = tid >> 5;        // token group 0..7
    const int l   = tid & 31;        // lane within half-wave
    const int m0  = tg * 4;          // first token of this half-wave's group
    const int eLo = l * 4;           // low expert quad; high quad at eLo+128

    // staging mapping
    const int sxm = tid >> 3;        // token row 0..31
    const int sxk = (tid & 7) * 4;   // k offset 0..28

    const float* xrow = x + (trow0 + sxm) * (long)HID + sxk;
    const float* wrow = w + (long)tid * HID;   // thread tid stages expert tid

    double acc[4][8];
#pragma unroll
    for (int i = 0; i < 4; ++i)
#pragma unroll
        for (int j = 0; j < 8; ++j) acc[i][j] = 0.0;

    // ---- stage chunk 0 ----
    {
        float4 a = *(const float4*)xrow;
        lds_x[(sxk + 0) * XSTR + sxm] = a.x;
        lds_x[(sxk + 1) * XSTR + sxm] = a.y;
        lds_x[(sxk + 2) * XSTR + sxm] = a.z;
        lds_x[(sxk + 3) * XSTR + sxm] = a.w;
#pragma unroll
        for (int q = 0; q < 8; ++q) {
            float4 v = *(const float4*)(wrow + q * 4);
            lds_w[(q * 4 + 0) * NEXP + tid] = v.x;
            lds_w[(q * 4 + 1) * NEXP + tid] = v.y;
            lds_w[(q * 4 + 2) * NEXP + tid] = v.z;
            lds_w[(q * 4 + 3) * NEXP + tid] = v.w;
        }
    }
    __syncthreads();

    // ---- K loop, register double-buffer prefetch ----
    for (int c = 0; c < NCHUNK; ++c) {
        float4 xr;
        float  wr[32];
        const bool has_next = (c + 1 < NCHUNK);
        const int  k0n = (c + 1) * BK;
        if (has_next) {
            xr = *(const float4*)(xrow + k0n);
#pragma unroll
            for (int q = 0; q < 8; ++q) {
                float4 v = *(const float4*)(wrow + k0n + q * 4);
                wr[q*4+0] = v.x; wr[q*4+1] = v.y; wr[q*4+2] = v.z; wr[q*4+3] = v.w;
            }
        }
#pragma unroll 4
        for (int kk = 0; kk < BK; ++kk) {
            float4 xa = *(const float4*)&lds_x[kk * XSTR + m0];
            float4 wa = *(const float4*)&lds_w[kk * NEXP + eLo];
            float4 wb = *(const float4*)&lds_w[kk * NEXP + eLo + 128];
            double xd[4] = {(double)xa.x, (double)xa.y, (double)xa.z, (double)xa.w};
            double wd[8] = {(double)wa.x, (double)wa.y, (double)wa.z, (double)wa.w,
                            (double)wb.x, (double)wb.y, (double)wb.z, (double)wb.w};
#pragma unroll
            for (int i = 0; i < 4; ++i)
#pragma unroll
                for (int j = 0; j < 8; ++j)
                    acc[i][j] = fma(xd[i], wd[j], acc[i][j]);
        }
        __syncthreads();
        if (has_next) {
            lds_x[(sxk + 0) * XSTR + sxm] = xr.x;
            lds_x[(sxk + 1) * XSTR + sxm] = xr.y;
            lds_x[(sxk + 2) * XSTR + sxm] = xr.z;
            lds_x[(sxk + 3) * XSTR + sxm] = xr.w;
#pragma unroll
            for (int q = 0; q < 32; ++q) lds_w[q * NEXP + tid] = wr[q];
        }
        __syncthreads();
    }

    // ---- gating, all fp64, per half-wave (32 lanes, 4 tokens) ----
    const int lane = tid & 63;
    const int half = lane & 32;   // shuffle base of my half-wave

    double bb[8];
    {
        float4 b0 = *(const float4*)&bias[eLo];
        float4 b1 = *(const float4*)&bias[eLo + 128];
        bb[0] = b0.x; bb[1] = b0.y; bb[2] = b0.z; bb[3] = b0.w;
        bb[4] = b1.x; bb[5] = b1.y; bb[6] = b1.z; bb[7] = b1.w;
    }

    float* out_idx = out;
    float* out_w   = out + (long)T_TOT * 8;

    const int myGLo = l >> 3;     // group of low quad; high quad group = myGLo+4

    for (int i = 0; i < 4; ++i) {
        const long t = trow0 + m0 + i;
        double sc[8], cs[8];
#pragma unroll
        for (int j = 0; j < 8; ++j) {
            sc[j] = 1.0 / (1.0 + exp(-acc[i][j]));
            cs[j] = sc[j] + bb[j];
        }

        // top-2 of each quad (low quad -> group myGLo, high quad -> myGLo+4)
        double l1, l2, h1, h2;
        {
            l1 = fmax(cs[0], cs[1]); l2 = fmin(cs[0], cs[1]);
            double n1 = fmax(l1, cs[2]); double n2 = fmax(fmin(l1, cs[2]), l2); l1 = n1; l2 = n2;
            n1 = fmax(l1, cs[3]); n2 = fmax(fmin(l1, cs[3]), l2); l1 = n1; l2 = n2;
            h1 = fmax(cs[4], cs[5]); h2 = fmin(cs[4], cs[5]);
            n1 = fmax(h1, cs[6]); n2 = fmax(fmin(h1, cs[6]), h2); h1 = n1; h2 = n2;
            n1 = fmax(h1, cs[7]); n2 = fmax(fmin(h1, cs[7]), h2); h1 = n1; h2 = n2;
        }
        // reduce top-2 across the 8 lanes sharing myGLo (xor 1,2,4 stays in half-wave)
#pragma unroll
        for (int d = 1; d < 8; d <<= 1) {
            double o1 = __shfl_xor(l1, d), o2 = __shfl_xor(l2, d);
            double n1 = fmax(l1, o1);
            double n2 = fmax(fmin(l1, o1), fmax(l2, o2));
            l1 = n1; l2 = n2;
            o1 = __shfl_xor(h1, d); o2 = __shfl_xor(h2, d);
            n1 = fmax(h1, o1);
            n2 = fmax(fmin(h1, o1), fmax(h2, o2));
            h1 = n1; h2 = n2;
        }
        const double gLo = l1 + l2;   // score of group myGLo
        const double gHi = h1 + h2;   // score of group myGLo+4

        // rank both of my groups among all 8 (tie -> lower group index)
        int rLo = 0, rHi = 0;
#pragma unroll
        for (int g = 0; g < 8; ++g) {
            double v = (g < 4) ? __shfl(gLo, half + g * 8)
                               : __shfl(gHi, half + (g - 4) * 8);
            rLo += (v > gLo || (v == gLo && g < myGLo)) ? 1 : 0;
            rHi += (v > gHi || (v == gHi && g < myGLo + 4)) ? 1 : 0;
        }
        const bool selLo = (rLo < 4);
        const bool selHi = (rHi < 4);

        double mv[8];
#pragma unroll
        for (int j = 0; j < 8; ++j)
            mv[j] = ((j < 4) ? selLo : selHi) ? cs[j] : -INFINITY;

        // iterative top-8 over 32 lanes x 8 experts (value desc, index asc on ties)
        double wsum = 0.0, my_w = 0.0;
        int my_ii = 0;
#pragma unroll
        for (int k = 0; k < 8; ++k) {
            double bv = mv[0]; int bj = 0;
            if (mv[1] > bv) { bv = mv[1]; bj = 1; }
            if (mv[2] > bv) { bv = mv[2]; bj = 2; }
            if (mv[3] > bv) { bv = mv[3]; bj = 3; }
            if (mv[4] > bv) { bv = mv[4]; bj = 4; }
            if (mv[5] > bv) { bv = mv[5]; bj = 5; }
            if (mv[6] > bv) { bv = mv[6]; bj = 6; }
            if (mv[7] > bv) { bv = mv[7]; bj = 7; }
            double v = bv;
            int ii = (bj < 4) ? (eLo + bj) : (128 + eLo + (bj - 4));
#pragma unroll
            for (int d = 1; d < 32; d <<= 1) {
                double ov = __shfl_xor(v, d);
                int    oi = __shfl_xor(ii, d);
                if (ov > v || (ov == v && oi < ii)) { v = ov; ii = oi; }
            }
            // winner's uncorrected sigmoid score (ii uniform across half-wave)
            const int hi8 = ii >> 7;
            const int oj  = (ii & 3) + 4 * hi8;
            const int ol  = (ii & 127) >> 2;
            double ssel = (oj == 0) ? sc[0] : (oj == 1) ? sc[1] : (oj == 2) ? sc[2] :
                          (oj == 3) ? sc[3] : (oj == 4) ? sc[4] : (oj == 5) ? sc[5] :
                          (oj == 6) ? sc[6] : sc[7];
            double su = __shfl(ssel, half + ol);
            wsum += su;
            if (l == k) { my_ii = ii; my_w = su; }
            // mask the winner (only the owner lane matches)
#pragma unroll
            for (int j = 0; j < 8; ++j) {
                int jj = (j < 4) ? (eLo + j) : (128 + eLo + (j - 4));
                if (jj == ii) mv[j] = -INFINITY;
            }
        }

        const double scale = 2.5 / (wsum + 1e-20);
        if (l < 8) {
            out_idx[t * 8 + l] = (float)my_ii;
            out_w[t * 8 + l]   = (float)(my_w * scale);
        }
    }
}

extern "C" void kernel_launch(void* const* d_in, const int* in_sizes, int n_in,
                              void* d_out, int out_size, void* d_ws, size_t ws_size,
                              hipStream_t stream)
{
    const float* x    = (const float*)d_in[0];  // [4,4096,7168] fp32
    const float* w    = (const float*)d_in[1];  // [256,7168] fp32
    const float* bias = (const float*)d_in[2];  // [256] fp32
    float* out = (float*)d_out;                 // [T*8 idx | T*8 weight] as float

    dim3 grid(T_TOT / BM);   // 512 blocks
    dim3 block(256);
    moe_gate_fp64<<<grid, block, 0, stream>>>(x, w, bias, out);
}

// Round 3
// 946.758 us; speedup vs baseline: 2.2445x; 2.2445x over previous
//
#include <hip/hip_runtime.h>
#include <math.h>

// MoE gate: fp32 fast pass with decision-margin flagging + exact fp64 repair
// of flagged tokens. T=16384, H=7168, E=256, 8 groups, top4 groups, top8.
// Output (float*): [0..T*8) = topk_idx as float, [T*8..2*T*8) = topk_weight.

constexpr int T_TOT = 16384;
constexpr int HID   = 7168;
constexpr int NEXP  = 256;

// K1 geometry
constexpr int BM1  = 64;
constexpr int BK1  = 32;
constexpr int NCH1 = HID / BK1;   // 224
constexpr int XPAD = 36;          // lds_x row stride (32+4)

// margin thresholds (score scale). fp32 score error <= ~2e-6 (6 sigma);
// thresholds give >10x safety.
constexpr float ETHR = 3e-5f;
constexpr float GTHR = 6e-5f;

constexpr int LISTCAP = 16384;

// repair geometry
constexpr int KSEG = 8;
constexpr int SEGK = HID / KSEG;  // 896
constexpr int TB2  = 8;           // tokens per repair block

// ---------------------------------------------------------------------------
// Kernel 1: fp32 fused gate + flags
// ---------------------------------------------------------------------------
__global__ __launch_bounds__(512)
void gate_fp32(const float* __restrict__ x, const float* __restrict__ w,
               const float* __restrict__ bias, float* __restrict__ out,
               int* __restrict__ cnt, int* __restrict__ list)
{
    __shared__ __align__(16) float lds_w[BK1 * NEXP];   // [k][e]
    __shared__ __align__(16) float lds_x[BM1 * XPAD];   // [m][k+pad]

    const int tid = threadIdx.x;
    const long trow0 = (long)blockIdx.x * BM1;

    const int l  = tid & 31;          // lane in half-wave
    const int m0 = (tid >> 5) * 4;    // 16 half-waves x 4 tokens = 64

    // staging maps
    const int sxm = tid >> 3;         // 0..63
    const int sxk = (tid & 7) * 4;    // 0..28
    const int we  = tid >> 1;         // 0..255
    const int wk0 = (tid & 1) * 16;   // 0/16

    const float* xrow = x + (trow0 + sxm) * (long)HID + sxk;
    const float* wrow = w + (long)we * HID + wk0;

    float acc[4][8];
#pragma unroll
    for (int i = 0; i < 4; ++i)
#pragma unroll
        for (int j = 0; j < 8; ++j) acc[i][j] = 0.0f;

    // stage chunk 0
    {
        float4 xa = *(const float4*)xrow;
        *(float4*)&lds_x[sxm * XPAD + sxk] = xa;
#pragma unroll
        for (int q = 0; q < 4; ++q) {
            float4 v = *(const float4*)(wrow + q * 4);
            lds_w[(wk0 + q*4 + 0) * NEXP + we] = v.x;
            lds_w[(wk0 + q*4 + 1) * NEXP + we] = v.y;
            lds_w[(wk0 + q*4 + 2) * NEXP + we] = v.z;
            lds_w[(wk0 + q*4 + 3) * NEXP + we] = v.w;
        }
    }
    __syncthreads();

    for (int c = 0; c < NCH1; ++c) {
        float4 xr;
        float4 wr[4];
        const bool hn = (c + 1 < NCH1);
        const int k0n = (c + 1) * BK1;
        if (hn) {
            xr = *(const float4*)(xrow + k0n);
#pragma unroll
            for (int q = 0; q < 4; ++q)
                wr[q] = *(const float4*)(wrow + k0n + q * 4);
        }
#pragma unroll 2
        for (int kq = 0; kq < 8; ++kq) {
            float xs_[4][4];
#pragma unroll
            for (int i = 0; i < 4; ++i) {
                float4 xq = *(const float4*)&lds_x[(m0 + i) * XPAD + kq * 4];
                xs_[i][0] = xq.x; xs_[i][1] = xq.y; xs_[i][2] = xq.z; xs_[i][3] = xq.w;
            }
#pragma unroll
            for (int kk = 0; kk < 4; ++kk) {
                float4 wa = *(const float4*)&lds_w[(kq*4 + kk) * NEXP + 4*l];
                float4 wb = *(const float4*)&lds_w[(kq*4 + kk) * NEXP + 4*l + 128];
#pragma unroll
                for (int i = 0; i < 4; ++i) {
                    const float xv = xs_[i][kk];
                    acc[i][0] = fmaf(xv, wa.x, acc[i][0]);
                    acc[i][1] = fmaf(xv, wa.y, acc[i][1]);
                    acc[i][2] = fmaf(xv, wa.z, acc[i][2]);
                    acc[i][3] = fmaf(xv, wa.w, acc[i][3]);
                    acc[i][4] = fmaf(xv, wb.x, acc[i][4]);
                    acc[i][5] = fmaf(xv, wb.y, acc[i][5]);
                    acc[i][6] = fmaf(xv, wb.z, acc[i][6]);
                    acc[i][7] = fmaf(xv, wb.w, acc[i][7]);
                }
            }
        }
        __syncthreads();
        if (hn) {
            *(float4*)&lds_x[sxm * XPAD + sxk] = xr;
#pragma unroll
            for (int q = 0; q < 4; ++q) {
                lds_w[(wk0 + q*4 + 0) * NEXP + we] = wr[q].x;
                lds_w[(wk0 + q*4 + 1) * NEXP + we] = wr[q].y;
                lds_w[(wk0 + q*4 + 2) * NEXP + we] = wr[q].z;
                lds_w[(wk0 + q*4 + 3) * NEXP + we] = wr[q].w;
            }
        }
        __syncthreads();
    }

    // ---- gating (fp32 port of validated fp64 gating) + margin flags ----
    const int lane  = tid & 63;
    const int hbase = lane & 32;
    const int myGLo = l >> 3;

    float bb[8];
    {
        float4 b0 = *(const float4*)&bias[4*l];
        float4 b1 = *(const float4*)&bias[4*l + 128];
        bb[0]=b0.x; bb[1]=b0.y; bb[2]=b0.z; bb[3]=b0.w;
        bb[4]=b1.x; bb[5]=b1.y; bb[6]=b1.z; bb[7]=b1.w;
    }

    float* out_idx = out;
    float* out_w   = out + (long)T_TOT * 8;

    for (int i = 0; i < 4; ++i) {
        const long t = trow0 + m0 + i;
        float sc[8], cs[8];
#pragma unroll
        for (int j = 0; j < 8; ++j) {
            sc[j] = 1.0f / (1.0f + expf(-acc[i][j]));
            cs[j] = sc[j] + bb[j];
        }
        // top-2 of each quad
        float l1, l2, h1, h2;
        {
            l1 = fmaxf(cs[0], cs[1]); l2 = fminf(cs[0], cs[1]);
            float n1 = fmaxf(l1, cs[2]); float n2 = fmaxf(fminf(l1, cs[2]), l2); l1=n1; l2=n2;
            n1 = fmaxf(l1, cs[3]); n2 = fmaxf(fminf(l1, cs[3]), l2); l1=n1; l2=n2;
            h1 = fmaxf(cs[4], cs[5]); h2 = fminf(cs[4], cs[5]);
            n1 = fmaxf(h1, cs[6]); n2 = fmaxf(fminf(h1, cs[6]), h2); h1=n1; h2=n2;
            n1 = fmaxf(h1, cs[7]); n2 = fmaxf(fminf(h1, cs[7]), h2); h1=n1; h2=n2;
        }
#pragma unroll
        for (int d = 1; d < 8; d <<= 1) {
            float o1 = __shfl_xor(l1, d), o2 = __shfl_xor(l2, d);
            float n1 = fmaxf(l1, o1);
            float n2 = fmaxf(fminf(l1, o1), fmaxf(l2, o2));
            l1 = n1; l2 = n2;
            o1 = __shfl_xor(h1, d); o2 = __shfl_xor(h2, d);
            n1 = fmaxf(h1, o1);
            n2 = fmaxf(fminf(h1, o1), fmaxf(h2, o2));
            h1 = n1; h2 = n2;
        }
        const float gLo = l1 + l2;
        const float gHi = h1 + h2;

        int rLo = 0, rHi = 0;
#pragma unroll
        for (int g = 0; g < 8; ++g) {
            float v = (g < 4) ? __shfl(gLo, hbase + g * 8)
                              : __shfl(gHi, hbase + (g - 4) * 8);
            rLo += (v > gLo || (v == gLo && g < myGLo)) ? 1 : 0;
            rHi += (v > gHi || (v == gHi && g < myGLo + 4)) ? 1 : 0;
        }
        const bool selLo = (rLo < 4);
        const bool selHi = (rHi < 4);

        // group-selection margin
        float selMin =  INFINITY, unsMax = -INFINITY;
        if (selLo) selMin = gLo; else unsMax = gLo;
        if (selHi) selMin = fminf(selMin, gHi); else unsMax = fmaxf(unsMax, gHi);
#pragma unroll
        for (int d = 1; d < 32; d <<= 1) {
            selMin = fminf(selMin, __shfl_xor(selMin, d));
            unsMax = fmaxf(unsMax, __shfl_xor(unsMax, d));
        }
        const float ggap = selMin - unsMax;

        float mv[8];
#pragma unroll
        for (int j = 0; j < 8; ++j)
            mv[j] = ((j < 4) ? selLo : selHi) ? cs[j] : -INFINITY;

        float wsum = 0.0f, my_w = 0.0f;
        int my_ii = 0;
        float prevv = 0.0f, mingap = INFINITY;
#pragma unroll
        for (int k = 0; k < 9; ++k) {
            float bv = mv[0]; int bj = 0;
            if (mv[1] > bv) { bv = mv[1]; bj = 1; }
            if (mv[2] > bv) { bv = mv[2]; bj = 2; }
            if (mv[3] > bv) { bv = mv[3]; bj = 3; }
            if (mv[4] > bv) { bv = mv[4]; bj = 4; }
            if (mv[5] > bv) { bv = mv[5]; bj = 5; }
            if (mv[6] > bv) { bv = mv[6]; bj = 6; }
            if (mv[7] > bv) { bv = mv[7]; bj = 7; }
            float v = bv;
            int ii = (bj < 4) ? (4*l + bj) : (128 + 4*l + (bj - 4));
#pragma unroll
            for (int d = 1; d < 32; d <<= 1) {
                float ov = __shfl_xor(v, d);
                int   oi = __shfl_xor(ii, d);
                if (ov > v || (ov == v && oi < ii)) { v = ov; ii = oi; }
            }
            if (k) mingap = fminf(mingap, prevv - v);
            prevv = v;
            if (k < 8) {
                const int hi8 = ii >> 7;
                const int oj  = (ii & 3) + 4 * hi8;
                const int ol  = (ii & 127) >> 2;
                float ssel = (oj == 0) ? sc[0] : (oj == 1) ? sc[1] : (oj == 2) ? sc[2] :
                             (oj == 3) ? sc[3] : (oj == 4) ? sc[4] : (oj == 5) ? sc[5] :
                             (oj == 6) ? sc[6] : sc[7];
                float su = __shfl(ssel, hbase + ol);
                wsum += su;
                if (l == k) { my_ii = ii; my_w = su; }
#pragma unroll
                for (int j = 0; j < 8; ++j) {
                    int jj = (j < 4) ? (4*l + j) : (128 + 4*l + (j - 4));
                    if (jj == ii) mv[j] = -INFINITY;
                }
            }
        }

        const float scale = 2.5f / (wsum + 1e-20f);
        if (l < 8) {
            out_idx[t * 8 + l] = (float)my_ii;
            out_w[t * 8 + l]   = my_w * scale;
        }
        const bool flag = (mingap < ETHR) || (ggap < GTHR);
        if (flag && l == 0) {
            int pos = atomicAdd(cnt, 1);
            if (pos < LISTCAP) list[pos] = (int)t;
        }
    }
}

// ---------------------------------------------------------------------------
// Kernel 2: fp64 partial dots for flagged tokens (K-split)
// ---------------------------------------------------------------------------
__global__ __launch_bounds__(256)
void repair_partial(const float* __restrict__ x, const float* __restrict__ w,
                    const int* __restrict__ list, const int* __restrict__ cntp,
                    double* __restrict__ part, int base, int cap)
{
    __shared__ __align__(16) float xls[TB2 * SEGK];   // 28.7 KB
    __shared__ int tokls[TB2];
    const int tid = threadIdx.x;
    const int ks  = blockIdx.y;

    int cnt = *cntp;
    if (cnt > 2 * cap)  cnt = 2 * cap;
    if (cnt > LISTCAP)  cnt = LISTCAP;
    const int cEnd = min(cnt, base + cap);

    for (int s0 = base + blockIdx.x * TB2; s0 < cEnd; s0 += gridDim.x * TB2) {
        if (tid < TB2) {
            int slot = s0 + tid;
            tokls[tid] = (slot < cEnd) ? list[slot] : 0;
        }
        __syncthreads();
        for (int q = tid; q < TB2 * (SEGK / 4); q += 256) {
            int i = q / (SEGK / 4), f = q % (SEGK / 4);
            float4 v = *(const float4*)(x + (long)tokls[i] * HID + ks * SEGK + f * 4);
            *(float4*)&xls[i * SEGK + f * 4] = v;
        }
        __syncthreads();

        double acc[TB2];
#pragma unroll
        for (int i = 0; i < TB2; ++i) acc[i] = 0.0;

        const float4* wp = (const float4*)(w + (long)tid * HID + ks * SEGK);
        for (int kb = 0; kb < SEGK / 4; ++kb) {
            float4 wv = wp[kb];
            double w0 = wv.x, w1 = wv.y, w2 = wv.z, w3 = wv.w;
#pragma unroll
            for (int i = 0; i < TB2; ++i) {
                float4 xv = *(const float4*)&xls[i * SEGK + kb * 4];
                acc[i] = fma((double)xv.x, w0, acc[i]);
                acc[i] = fma((double)xv.y, w1, acc[i]);
                acc[i] = fma((double)xv.z, w2, acc[i]);
                acc[i] = fma((double)xv.w, w3, acc[i]);
            }
        }
#pragma unroll
        for (int i = 0; i < TB2; ++i) {
            long pofs = (((long)(s0 - base) + i) * KSEG + ks) * NEXP + tid;
            part[pofs] = acc[i];
        }
        __syncthreads();
    }
}

// ---------------------------------------------------------------------------
// Kernel 3: reduce partials + exact fp64 gating for flagged tokens
// ---------------------------------------------------------------------------
__global__ __launch_bounds__(256)
void repair_gate(const float* __restrict__ bias, const int* __restrict__ list,
                 const int* __restrict__ cntp, const double* __restrict__ part,
                 float* __restrict__ out, int base, int cap)
{
    __shared__ double lgl[TB2 * NEXP];   // 16 KB
    __shared__ int tokls[TB2];
    const int tid = threadIdx.x;

    int cnt = *cntp;
    if (cnt > 2 * cap)  cnt = 2 * cap;
    if (cnt > LISTCAP)  cnt = LISTCAP;
    const int cEnd = min(cnt, base + cap);

    float* out_idx = out;
    float* out_w   = out + (long)T_TOT * 8;

    const int l     = tid & 31;
    const int lane  = tid & 63;
    const int hbase = lane & 32;
    const int hw    = tid >> 5;      // 0..7: token slot within batch
    const int myGLo = l >> 3;

    double bb[8];
    {
        float4 b0 = *(const float4*)&bias[4*l];
        float4 b1 = *(const float4*)&bias[4*l + 128];
        bb[0]=b0.x; bb[1]=b0.y; bb[2]=b0.z; bb[3]=b0.w;
        bb[4]=b1.x; bb[5]=b1.y; bb[6]=b1.z; bb[7]=b1.w;
    }

    for (int s0 = base + blockIdx.x * TB2; s0 < cEnd; s0 += gridDim.x * TB2) {
        if (tid < TB2) {
            int slot = s0 + tid;
            tokls[tid] = (slot < cEnd) ? list[slot] : 0;
        }
#pragma unroll
        for (int i = 0; i < TB2; ++i) {
            long pbase = (((long)(s0 - base) + i) * KSEG) * NEXP + tid;
            double s = 0.0;
#pragma unroll
            for (int ks = 0; ks < KSEG; ++ks) s += part[pbase + ks * NEXP];
            lgl[i * NEXP + tid] = s;
        }
        __syncthreads();
        {
            const int slot = s0 + hw;
            const bool valid = (slot < cEnd);
            const long t = tokls[hw];

            double sc[8], cs[8];
#pragma unroll
            for (int j = 0; j < 4; ++j) {
                double lg = lgl[hw * NEXP + 4*l + j];
                sc[j] = 1.0 / (1.0 + exp(-lg));
                cs[j] = sc[j] + bb[j];
            }
#pragma unroll
            for (int j = 4; j < 8; ++j) {
                double lg = lgl[hw * NEXP + 128 + 4*l + (j - 4)];
                sc[j] = 1.0 / (1.0 + exp(-lg));
                cs[j] = sc[j] + bb[j];
            }

            double l1, l2, h1, h2;
            {
                l1 = fmax(cs[0], cs[1]); l2 = fmin(cs[0], cs[1]);
                double n1 = fmax(l1, cs[2]); double n2 = fmax(fmin(l1, cs[2]), l2); l1=n1; l2=n2;
                n1 = fmax(l1, cs[3]); n2 = fmax(fmin(l1, cs[3]), l2); l1=n1; l2=n2;
                h1 = fmax(cs[4], cs[5]); h2 = fmin(cs[4], cs[5]);
                n1 = fmax(h1, cs[6]); n2 = fmax(fmin(h1, cs[6]), h2); h1=n1; h2=n2;
                n1 = fmax(h1, cs[7]); n2 = fmax(fmin(h1, cs[7]), h2); h1=n1; h2=n2;
            }
#pragma unroll
            for (int d = 1; d < 8; d <<= 1) {
                double o1 = __shfl_xor(l1, d), o2 = __shfl_xor(l2, d);
                double n1 = fmax(l1, o1);
                double n2 = fmax(fmin(l1, o1), fmax(l2, o2));
                l1 = n1; l2 = n2;
                o1 = __shfl_xor(h1, d); o2 = __shfl_xor(h2, d);
                n1 = fmax(h1, o1);
                n2 = fmax(fmin(h1, o1), fmax(h2, o2));
                h1 = n1; h2 = n2;
            }
            const double gLo = l1 + l2;
            const double gHi = h1 + h2;

            int rLo = 0, rHi = 0;
#pragma unroll
            for (int g = 0; g < 8; ++g) {
                double v = (g < 4) ? __shfl(gLo, hbase + g * 8)
                                   : __shfl(gHi, hbase + (g - 4) * 8);
                rLo += (v > gLo || (v == gLo && g < myGLo)) ? 1 : 0;
                rHi += (v > gHi || (v == gHi && g < myGLo + 4)) ? 1 : 0;
            }
            const bool selLo = (rLo < 4);
            const bool selHi = (rHi < 4);

            double mv[8];
#pragma unroll
            for (int j = 0; j < 8; ++j)
                mv[j] = ((j < 4) ? selLo : selHi) ? cs[j] : -INFINITY;

            double wsum = 0.0, my_w = 0.0;
            int my_ii = 0;
#pragma unroll
            for (int k = 0; k < 8; ++k) {
                double bv = mv[0]; int bj = 0;
                if (mv[1] > bv) { bv = mv[1]; bj = 1; }
                if (mv[2] > bv) { bv = mv[2]; bj = 2; }
                if (mv[3] > bv) { bv = mv[3]; bj = 3; }
                if (mv[4] > bv) { bv = mv[4]; bj = 4; }
                if (mv[5] > bv) { bv = mv[5]; bj = 5; }
                if (mv[6] > bv) { bv = mv[6]; bj = 6; }
                if (mv[7] > bv) { bv = mv[7]; bj = 7; }
                double v = bv;
                int ii = (bj < 4) ? (4*l + bj) : (128 + 4*l + (bj - 4));
#pragma unroll
                for (int d = 1; d < 32; d <<= 1) {
                    double ov = __shfl_xor(v, d);
                    int    oi = __shfl_xor(ii, d);
                    if (ov > v || (ov == v && oi < ii)) { v = ov; ii = oi; }
                }
                const int hi8 = ii >> 7;
                const int oj  = (ii & 3) + 4 * hi8;
                const int ol  = (ii & 127) >> 2;
                double ssel = (oj == 0) ? sc[0] : (oj == 1) ? sc[1] : (oj == 2) ? sc[2] :
                              (oj == 3) ? sc[3] : (oj == 4) ? sc[4] : (oj == 5) ? sc[5] :
                              (oj == 6) ? sc[6] : sc[7];
                double su = __shfl(ssel, hbase + ol);
                wsum += su;
                if (l == k) { my_ii = ii; my_w = su; }
#pragma unroll
                for (int j = 0; j < 8; ++j) {
                    int jj = (j < 4) ? (4*l + j) : (128 + 4*l + (j - 4));
                    if (jj == ii) mv[j] = -INFINITY;
                }
            }

            const double scale = 2.5 / (wsum + 1e-20);
            if (valid && l < 8) {
                out_idx[t * 8 + l] = (float)my_ii;
                out_w[t * 8 + l]   = (float)(my_w * scale);
            }
        }
        __syncthreads();
    }
}

// ---------------------------------------------------------------------------
extern "C" void kernel_launch(void* const* d_in, const int* in_sizes, int n_in,
                              void* d_out, int out_size, void* d_ws, size_t ws_size,
                              hipStream_t stream)
{
    const float* x    = (const float*)d_in[0];
    const float* w    = (const float*)d_in[1];
    const float* bias = (const float*)d_in[2];
    float* out = (float*)d_out;

    int*    cnt  = (int*)d_ws;
    int*    list = (int*)((char*)d_ws + 256);
    double* part = (double*)((char*)d_ws + 66048);

    size_t avail = (ws_size > 66048) ? (ws_size - 66048) : 0;
    long cap_l = (long)(avail / ((size_t)KSEG * NEXP * 8));   // 16 KB per slot
    int CAP = (int)(cap_l > 4096 ? 4096 : cap_l);

    hipMemsetAsync(d_ws, 0, 4, stream);   // zero flag counter
    gate_fp32<<<T_TOT / BM1, 512, 0, stream>>>(x, w, bias, out, cnt, list);
    if (CAP > 0) {
        for (int p = 0; p < 2; ++p) {
            repair_partial<<<dim3(128, KSEG), 256, 0, stream>>>(x, w, list, cnt, part, p * CAP, CAP);
            repair_gate<<<64, 256, 0, stream>>>(bias, list, cnt, part, out, p * CAP, CAP);
        }
    }
}

// Round 4
// 848.989 us; speedup vs baseline: 2.5030x; 1.1152x over previous
//
#include <hip/hip_runtime.h>
#include <math.h>

// MoE gate: bf16x3 split-precision MFMA GEMM + fp32 gating with decision-margin
// flagging + exact fp64 repair of flagged tokens.
// T=16384, H=7168, E=256, 8 groups, top4 groups, top8 experts.
// Output (float*): [0..T*8) = topk_idx as float, [T*8..2*T*8) = topk_weight.

typedef __bf16 bf16_t;
typedef __bf16 bf16x8 __attribute__((ext_vector_type(8)));
typedef float  f32x4  __attribute__((ext_vector_type(4)));

constexpr int T_TOT = 16384;
constexpr int HID   = 7168;
constexpr int NEXP  = 256;

// gate geometry
constexpr int BM1  = 64;
constexpr int BK1  = 32;
constexpr int NCH1 = HID / BK1;   // 224
constexpr int BSTR = 40;          // padded LDS row stride (bf16) for A/B tiles
constexpr int LSTR = 264;         // logits row stride (f32)

// margin thresholds (score scale). bf16x3 score error 6-sigma ~= 4e-5;
// thresholds give ~30x sigma safety.
constexpr float ETHR = 1.2e-4f;
constexpr float GTHR = 2.4e-4f;

constexpr int LISTCAP = 16384;

// repair geometry
constexpr int KSEG = 8;
constexpr int SEGK = HID / KSEG;  // 896
constexpr int TB2  = 8;           // tokens per repair block

// ---------------------------------------------------------------------------
// Kernel 0: split W fp32 -> chunk-major bf16 hi/lo  wpack[c][e][32]
// ---------------------------------------------------------------------------
__global__ __launch_bounds__(256)
void prep_w(const float* __restrict__ w, bf16_t* __restrict__ whi,
            bf16_t* __restrict__ wlo)
{
    const int gid = blockIdx.x * 256 + threadIdx.x;   // 229376 total
    const int e   = gid / (HID / 8);
    const int k8  = gid - e * (HID / 8);
    const int k0  = k8 * 8;
    const int c   = k0 >> 5;          // chunk index
    const int kk  = k0 & 31;

    float4 f0 = *(const float4*)(w + (long)e * HID + k0);
    float4 f1 = *(const float4*)(w + (long)e * HID + k0 + 4);
    float fv[8] = {f0.x, f0.y, f0.z, f0.w, f1.x, f1.y, f1.z, f1.w};
    bf16x8 hv, lv;
#pragma unroll
    for (int j = 0; j < 8; ++j) {
        bf16_t h = (bf16_t)fv[j];
        hv[j] = h;
        lv[j] = (bf16_t)(fv[j] - (float)h);
    }
    const long ofs = ((long)c * NEXP + e) * 32 + kk;
    *(bf16x8*)(whi + ofs) = hv;
    *(bf16x8*)(wlo + ofs) = lv;
}

// ---------------------------------------------------------------------------
// Kernel 1: MFMA gate + flags
// ---------------------------------------------------------------------------
__global__ __launch_bounds__(256, 2)
void gate_mfma(const float* __restrict__ x, const bf16_t* __restrict__ whi,
               const bf16_t* __restrict__ wlo, const float* __restrict__ bias,
               float* __restrict__ out, int* __restrict__ cnt,
               int* __restrict__ list)
{
    __shared__ __align__(16) unsigned char smem[BM1 * LSTR * 4];  // 67584 B
    bf16_t* a_hi = (bf16_t*)smem;              // [64][40]
    bf16_t* a_lo = a_hi + BM1 * BSTR;
    bf16_t* b_hi = a_lo + BM1 * BSTR;          // [256][40]
    bf16_t* b_lo = b_hi + NEXP * BSTR;
    float*  lgl  = (float*)smem;               // [64][264] (epilogue alias)

    const int tid = threadIdx.x;
    const int bid = blockIdx.x;
    const int swz = (bid & 7) * 32 + (bid >> 3);   // XCD-aware swizzle (256%8==0)
    const long trow0 = (long)swz * BM1;

    const int lane = tid & 63;
    const int wid  = tid >> 6;        // wave 0..3 -> experts [64w, 64w+64)
    const int lr   = lane & 15;
    const int kg   = (lane >> 4) * 8; // k-octet base
    const int we0  = wid * 64;

    // x staging map: thread -> (token row, k-octet)
    const int sxm = tid >> 2;         // 0..63
    const int sxk = (tid & 3) * 8;    // 0,8,16,24
    const float* xrow = x + (trow0 + sxm) * (long)HID + sxk;

    f32x4 acc[4][4] = {};

    // ---- stage chunk 0 ----
    {
        float4 f0 = *(const float4*)(xrow);
        float4 f1 = *(const float4*)(xrow + 4);
        float fv[8] = {f0.x, f0.y, f0.z, f0.w, f1.x, f1.y, f1.z, f1.w};
        bf16x8 h, l;
#pragma unroll
        for (int j = 0; j < 8; ++j) {
            bf16_t hh = (bf16_t)fv[j];
            h[j] = hh;
            l[j] = (bf16_t)(fv[j] - (float)hh);
        }
        *(bf16x8*)(a_hi + sxm * BSTR + sxk) = h;
        *(bf16x8*)(a_lo + sxm * BSTR + sxk) = l;
        const bf16_t* wh = whi + (long)tid * 32;
        const bf16_t* wl = wlo + (long)tid * 32;
#pragma unroll
        for (int q = 0; q < 4; ++q) {
            *(bf16x8*)(b_hi + tid * BSTR + q * 8) = *(const bf16x8*)(wh + q * 8);
            *(bf16x8*)(b_lo + tid * BSTR + q * 8) = *(const bf16x8*)(wl + q * 8);
        }
    }
    __syncthreads();

    // ---- K loop with register prefetch ----
    for (int c = 0; c < NCH1; ++c) {
        const bool hn = (c + 1 < NCH1);
        float fv[8];
        bf16x8 wrh[4], wrl[4];
        if (hn) {
            float4 f0 = *(const float4*)(xrow + (c + 1) * BK1);
            float4 f1 = *(const float4*)(xrow + (c + 1) * BK1 + 4);
            fv[0] = f0.x; fv[1] = f0.y; fv[2] = f0.z; fv[3] = f0.w;
            fv[4] = f1.x; fv[5] = f1.y; fv[6] = f1.z; fv[7] = f1.w;
            const bf16_t* wh = whi + ((long)(c + 1) * NEXP + tid) * 32;
            const bf16_t* wl = wlo + ((long)(c + 1) * NEXP + tid) * 32;
#pragma unroll
            for (int q = 0; q < 4; ++q) {
                wrh[q] = *(const bf16x8*)(wh + q * 8);
                wrl[q] = *(const bf16x8*)(wl + q * 8);
            }
        }
        // compute chunk c
        bf16x8 ah[4], al[4], bh[4], bl[4];
#pragma unroll
        for (int mi = 0; mi < 4; ++mi) {
            ah[mi] = *(const bf16x8*)(a_hi + (mi * 16 + lr) * BSTR + kg);
            al[mi] = *(const bf16x8*)(a_lo + (mi * 16 + lr) * BSTR + kg);
        }
#pragma unroll
        for (int ni = 0; ni < 4; ++ni) {
            bh[ni] = *(const bf16x8*)(b_hi + (we0 + ni * 16 + lr) * BSTR + kg);
            bl[ni] = *(const bf16x8*)(b_lo + (we0 + ni * 16 + lr) * BSTR + kg);
        }
#pragma unroll
        for (int mi = 0; mi < 4; ++mi)
#pragma unroll
            for (int ni = 0; ni < 4; ++ni) {
                acc[mi][ni] = __builtin_amdgcn_mfma_f32_16x16x32_bf16(ah[mi], bh[ni], acc[mi][ni], 0, 0, 0);
                acc[mi][ni] = __builtin_amdgcn_mfma_f32_16x16x32_bf16(ah[mi], bl[ni], acc[mi][ni], 0, 0, 0);
                acc[mi][ni] = __builtin_amdgcn_mfma_f32_16x16x32_bf16(al[mi], bh[ni], acc[mi][ni], 0, 0, 0);
            }
        __syncthreads();
        if (hn) {
            bf16x8 h, l;
#pragma unroll
            for (int j = 0; j < 8; ++j) {
                bf16_t hh = (bf16_t)fv[j];
                h[j] = hh;
                l[j] = (bf16_t)(fv[j] - (float)hh);
            }
            *(bf16x8*)(a_hi + sxm * BSTR + sxk) = h;
            *(bf16x8*)(a_lo + sxm * BSTR + sxk) = l;
#pragma unroll
            for (int q = 0; q < 4; ++q) {
                *(bf16x8*)(b_hi + tid * BSTR + q * 8) = wrh[q];
                *(bf16x8*)(b_lo + tid * BSTR + q * 8) = wrl[q];
            }
        }
        __syncthreads();
    }

    // ---- epilogue: logits -> LDS ----
#pragma unroll
    for (int mi = 0; mi < 4; ++mi)
#pragma unroll
        for (int ni = 0; ni < 4; ++ni)
#pragma unroll
            for (int r = 0; r < 4; ++r)
                lgl[(mi * 16 + (lane >> 4) * 4 + r) * LSTR + we0 + ni * 16 + lr] =
                    acc[mi][ni][r];
    __syncthreads();

    // ---- gating (fp32, proven in round 3) + margin flags ----
    const int l     = tid & 31;
    const int hbase = lane & 32;
    const int myGLo = l >> 3;
    const int m0    = (tid >> 5) * 8;   // 8 half-waves x 8 tokens = 64

    float bb[8];
    {
        float4 b0 = *(const float4*)&bias[4 * l];
        float4 b1 = *(const float4*)&bias[4 * l + 128];
        bb[0] = b0.x; bb[1] = b0.y; bb[2] = b0.z; bb[3] = b0.w;
        bb[4] = b1.x; bb[5] = b1.y; bb[6] = b1.z; bb[7] = b1.w;
    }

    float* out_idx = out;
    float* out_w   = out + (long)T_TOT * 8;

    for (int i = 0; i < 8; ++i) {
        const long t = trow0 + m0 + i;
        float4 lg0 = *(const float4*)&lgl[(m0 + i) * LSTR + 4 * l];
        float4 lg1 = *(const float4*)&lgl[(m0 + i) * LSTR + 128 + 4 * l];
        float lgv[8] = {lg0.x, lg0.y, lg0.z, lg0.w, lg1.x, lg1.y, lg1.z, lg1.w};
        float sc[8], cs[8];
#pragma unroll
        for (int j = 0; j < 8; ++j) {
            sc[j] = 1.0f / (1.0f + expf(-lgv[j]));
            cs[j] = sc[j] + bb[j];
        }
        // top-2 of each quad
        float l1, l2, h1, h2;
        {
            l1 = fmaxf(cs[0], cs[1]); l2 = fminf(cs[0], cs[1]);
            float n1 = fmaxf(l1, cs[2]); float n2 = fmaxf(fminf(l1, cs[2]), l2); l1 = n1; l2 = n2;
            n1 = fmaxf(l1, cs[3]); n2 = fmaxf(fminf(l1, cs[3]), l2); l1 = n1; l2 = n2;
            h1 = fmaxf(cs[4], cs[5]); h2 = fminf(cs[4], cs[5]);
            n1 = fmaxf(h1, cs[6]); n2 = fmaxf(fminf(h1, cs[6]), h2); h1 = n1; h2 = n2;
            n1 = fmaxf(h1, cs[7]); n2 = fmaxf(fminf(h1, cs[7]), h2); h1 = n1; h2 = n2;
        }
#pragma unroll
        for (int d = 1; d < 8; d <<= 1) {
            float o1 = __shfl_xor(l1, d), o2 = __shfl_xor(l2, d);
            float n1 = fmaxf(l1, o1);
            float n2 = fmaxf(fminf(l1, o1), fmaxf(l2, o2));
            l1 = n1; l2 = n2;
            o1 = __shfl_xor(h1, d); o2 = __shfl_xor(h2, d);
            n1 = fmaxf(h1, o1);
            n2 = fmaxf(fminf(h1, o1), fmaxf(h2, o2));
            h1 = n1; h2 = n2;
        }
        const float gLo = l1 + l2;
        const float gHi = h1 + h2;

        int rLo = 0, rHi = 0;
#pragma unroll
        for (int g = 0; g < 8; ++g) {
            float v = (g < 4) ? __shfl(gLo, hbase + g * 8)
                              : __shfl(gHi, hbase + (g - 4) * 8);
            rLo += (v > gLo || (v == gLo && g < myGLo)) ? 1 : 0;
            rHi += (v > gHi || (v == gHi && g < myGLo + 4)) ? 1 : 0;
        }
        const bool selLo = (rLo < 4);
        const bool selHi = (rHi < 4);

        float selMin =  INFINITY, unsMax = -INFINITY;
        if (selLo) selMin = gLo; else unsMax = gLo;
        if (selHi) selMin = fminf(selMin, gHi); else unsMax = fmaxf(unsMax, gHi);
#pragma unroll
        for (int d = 1; d < 32; d <<= 1) {
            selMin = fminf(selMin, __shfl_xor(selMin, d));
            unsMax = fmaxf(unsMax, __shfl_xor(unsMax, d));
        }
        const float ggap = selMin - unsMax;

        float mv[8];
#pragma unroll
        for (int j = 0; j < 8; ++j)
            mv[j] = ((j < 4) ? selLo : selHi) ? cs[j] : -INFINITY;

        float wsum = 0.0f, my_w = 0.0f;
        int my_ii = 0;
        float prevv = 0.0f, mingap = INFINITY;
#pragma unroll
        for (int k = 0; k < 9; ++k) {
            float bv = mv[0]; int bj = 0;
            if (mv[1] > bv) { bv = mv[1]; bj = 1; }
            if (mv[2] > bv) { bv = mv[2]; bj = 2; }
            if (mv[3] > bv) { bv = mv[3]; bj = 3; }
            if (mv[4] > bv) { bv = mv[4]; bj = 4; }
            if (mv[5] > bv) { bv = mv[5]; bj = 5; }
            if (mv[6] > bv) { bv = mv[6]; bj = 6; }
            if (mv[7] > bv) { bv = mv[7]; bj = 7; }
            float v = bv;
            int ii = (bj < 4) ? (4 * l + bj) : (128 + 4 * l + (bj - 4));
#pragma unroll
            for (int d = 1; d < 32; d <<= 1) {
                float ov = __shfl_xor(v, d);
                int   oi = __shfl_xor(ii, d);
                if (ov > v || (ov == v && oi < ii)) { v = ov; ii = oi; }
            }
            if (k) mingap = fminf(mingap, prevv - v);
            prevv = v;
            if (k < 8) {
                const int hi8 = ii >> 7;
                const int oj  = (ii & 3) + 4 * hi8;
                const int ol  = (ii & 127) >> 2;
                float ssel = (oj == 0) ? sc[0] : (oj == 1) ? sc[1] : (oj == 2) ? sc[2] :
                             (oj == 3) ? sc[3] : (oj == 4) ? sc[4] : (oj == 5) ? sc[5] :
                             (oj == 6) ? sc[6] : sc[7];
                float su = __shfl(ssel, hbase + ol);
                wsum += su;
                if (l == k) { my_ii = ii; my_w = su; }
#pragma unroll
                for (int j = 0; j < 8; ++j) {
                    int jj = (j < 4) ? (4 * l + j) : (128 + 4 * l + (j - 4));
                    if (jj == ii) mv[j] = -INFINITY;
                }
            }
        }

        const float scale = 2.5f / (wsum + 1e-20f);
        if (l < 8) {
            out_idx[t * 8 + l] = (float)my_ii;
            out_w[t * 8 + l]   = my_w * scale;
        }
        const bool flag = (mingap < ETHR) || (ggap < GTHR);
        if (flag && l == 0) {
            int pos = atomicAdd(cnt, 1);
            if (pos < LISTCAP) list[pos] = (int)t;
        }
    }
}

// ---------------------------------------------------------------------------
// Kernel 2: fp64 partial dots for flagged tokens (K-split)
// ---------------------------------------------------------------------------
__global__ __launch_bounds__(256)
void repair_partial(const float* __restrict__ x, const float* __restrict__ w,
                    const int* __restrict__ list, const int* __restrict__ cntp,
                    double* __restrict__ part, int base, int cap)
{
    __shared__ __align__(16) float xls[TB2 * SEGK];
    __shared__ int tokls[TB2];
    const int tid = threadIdx.x;
    const int ks  = blockIdx.y;

    int cnt = *cntp;
    if (cnt > 2 * cap)  cnt = 2 * cap;
    if (cnt > LISTCAP)  cnt = LISTCAP;
    const int cEnd = min(cnt, base + cap);

    for (int s0 = base + blockIdx.x * TB2; s0 < cEnd; s0 += gridDim.x * TB2) {
        if (tid < TB2) {
            int slot = s0 + tid;
            tokls[tid] = (slot < cEnd) ? list[slot] : 0;
        }
        __syncthreads();
        for (int q = tid; q < TB2 * (SEGK / 4); q += 256) {
            int i = q / (SEGK / 4), f = q % (SEGK / 4);
            float4 v = *(const float4*)(x + (long)tokls[i] * HID + ks * SEGK + f * 4);
            *(float4*)&xls[i * SEGK + f * 4] = v;
        }
        __syncthreads();

        double acc[TB2];
#pragma unroll
        for (int i = 0; i < TB2; ++i) acc[i] = 0.0;

        const float4* wp = (const float4*)(w + (long)tid * HID + ks * SEGK);
        for (int kb = 0; kb < SEGK / 4; ++kb) {
            float4 wv = wp[kb];
            double w0 = wv.x, w1 = wv.y, w2 = wv.z, w3 = wv.w;
#pragma unroll
            for (int i = 0; i < TB2; ++i) {
                float4 xv = *(const float4*)&xls[i * SEGK + kb * 4];
                acc[i] = fma((double)xv.x, w0, acc[i]);
                acc[i] = fma((double)xv.y, w1, acc[i]);
                acc[i] = fma((double)xv.z, w2, acc[i]);
                acc[i] = fma((double)xv.w, w3, acc[i]);
            }
        }
#pragma unroll
        for (int i = 0; i < TB2; ++i) {
            long pofs = (((long)(s0 - base) + i) * KSEG + ks) * NEXP + tid;
            part[pofs] = acc[i];
        }
        __syncthreads();
    }
}

// ---------------------------------------------------------------------------
// Kernel 3: reduce partials + exact fp64 gating for flagged tokens
// ---------------------------------------------------------------------------
__global__ __launch_bounds__(256)
void repair_gate(const float* __restrict__ bias, const int* __restrict__ list,
                 const int* __restrict__ cntp, const double* __restrict__ part,
                 float* __restrict__ out, int base, int cap)
{
    __shared__ double lgl[TB2 * NEXP];
    __shared__ int tokls[TB2];
    const int tid = threadIdx.x;

    int cnt = *cntp;
    if (cnt > 2 * cap)  cnt = 2 * cap;
    if (cnt > LISTCAP)  cnt = LISTCAP;
    const int cEnd = min(cnt, base + cap);

    float* out_idx = out;
    float* out_w   = out + (long)T_TOT * 8;

    const int l     = tid & 31;
    const int lane  = tid & 63;
    const int hbase = lane & 32;
    const int hw    = tid >> 5;
    const int myGLo = l >> 3;

    double bb[8];
    {
        float4 b0 = *(const float4*)&bias[4 * l];
        float4 b1 = *(const float4*)&bias[4 * l + 128];
        bb[0] = b0.x; bb[1] = b0.y; bb[2] = b0.z; bb[3] = b0.w;
        bb[4] = b1.x; bb[5] = b1.y; bb[6] = b1.z; bb[7] = b1.w;
    }

    for (int s0 = base + blockIdx.x * TB2; s0 < cEnd; s0 += gridDim.x * TB2) {
        if (tid < TB2) {
            int slot = s0 + tid;
            tokls[tid] = (slot < cEnd) ? list[slot] : 0;
        }
#pragma unroll
        for (int i = 0; i < TB2; ++i) {
            long pbase = (((long)(s0 - base) + i) * KSEG) * NEXP + tid;
            double s = 0.0;
#pragma unroll
            for (int ks = 0; ks < KSEG; ++ks) s += part[pbase + ks * NEXP];
            lgl[i * NEXP + tid] = s;
        }
        __syncthreads();
        {
            const int slot = s0 + hw;
            const bool valid = (slot < cEnd);
            const long t = tokls[hw];

            double sc[8], cs[8];
#pragma unroll
            for (int j = 0; j < 4; ++j) {
                double lg = lgl[hw * NEXP + 4 * l + j];
                sc[j] = 1.0 / (1.0 + exp(-lg));
                cs[j] = sc[j] + bb[j];
            }
#pragma unroll
            for (int j = 4; j < 8; ++j) {
                double lg = lgl[hw * NEXP + 128 + 4 * l + (j - 4)];
                sc[j] = 1.0 / (1.0 + exp(-lg));
                cs[j] = sc[j] + bb[j];
            }

            double l1, l2, h1, h2;
            {
                l1 = fmax(cs[0], cs[1]); l2 = fmin(cs[0], cs[1]);
                double n1 = fmax(l1, cs[2]); double n2 = fmax(fmin(l1, cs[2]), l2); l1 = n1; l2 = n2;
                n1 = fmax(l1, cs[3]); n2 = fmax(fmin(l1, cs[3]), l2); l1 = n1; l2 = n2;
                h1 = fmax(cs[4], cs[5]); h2 = fmin(cs[4], cs[5]);
                n1 = fmax(h1, cs[6]); n2 = fmax(fmin(h1, cs[6]), h2); h1 = n1; h2 = n2;
                n1 = fmax(h1, cs[7]); n2 = fmax(fmin(h1, cs[7]), h2); h1 = n1; h2 = n2;
            }
#pragma unroll
            for (int d = 1; d < 8; d <<= 1) {
                double o1 = __shfl_xor(l1, d), o2 = __shfl_xor(l2, d);
                double n1 = fmax(l1, o1);
                double n2 = fmax(fmin(l1, o1), fmax(l2, o2));
                l1 = n1; l2 = n2;
                o1 = __shfl_xor(h1, d); o2 = __shfl_xor(h2, d);
                n1 = fmax(h1, o1);
                n2 = fmax(fmin(h1, o1), fmax(h2, o2));
                h1 = n1; h2 = n2;
            }
            const double gLo = l1 + l2;
            const double gHi = h1 + h2;

            int rLo = 0, rHi = 0;
#pragma unroll
            for (int g = 0; g < 8; ++g) {
                double v = (g < 4) ? __shfl(gLo, hbase + g * 8)
                                   : __shfl(gHi, hbase + (g - 4) * 8);
                rLo += (v > gLo || (v == gLo && g < myGLo)) ? 1 : 0;
                rHi += (v > gHi || (v == gHi && g < myGLo + 4)) ? 1 : 0;
            }
            const bool selLo = (rLo < 4);
            const bool selHi = (rHi < 4);

            double mv[8];
#pragma unroll
            for (int j = 0; j < 8; ++j)
                mv[j] = ((j < 4) ? selLo : selHi) ? cs[j] : -INFINITY;

            double wsum = 0.0, my_w = 0.0;
            int my_ii = 0;
#pragma unroll
            for (int k = 0; k < 8; ++k) {
                double bv = mv[0]; int bj = 0;
                if (mv[1] > bv) { bv = mv[1]; bj = 1; }
                if (mv[2] > bv) { bv = mv[2]; bj = 2; }
                if (mv[3] > bv) { bv = mv[3]; bj = 3; }
                if (mv[4] > bv) { bv = mv[4]; bj = 4; }
                if (mv[5] > bv) { bv = mv[5]; bj = 5; }
                if (mv[6] > bv) { bv = mv[6]; bj = 6; }
                if (mv[7] > bv) { bv = mv[7]; bj = 7; }
                double v = bv;
                int ii = (bj < 4) ? (4 * l + bj) : (128 + 4 * l + (bj - 4));
#pragma unroll
                for (int d = 1; d < 32; d <<= 1) {
                    double ov = __shfl_xor(v, d);
                    int    oi = __shfl_xor(ii, d);
                    if (ov > v || (ov == v && oi < ii)) { v = ov; ii = oi; }
                }
                const int hi8 = ii >> 7;
                const int oj  = (ii & 3) + 4 * hi8;
                const int ol  = (ii & 127) >> 2;
                double ssel = (oj == 0) ? sc[0] : (oj == 1) ? sc[1] : (oj == 2) ? sc[2] :
                              (oj == 3) ? sc[3] : (oj == 4) ? sc[4] : (oj == 5) ? sc[5] :
                              (oj == 6) ? sc[6] : sc[7];
                double su = __shfl(ssel, hbase + ol);
                wsum += su;
                if (l == k) { my_ii = ii; my_w = su; }
#pragma unroll
                for (int j = 0; j < 8; ++j) {
                    int jj = (j < 4) ? (4 * l + j) : (128 + 4 * l + (j - 4));
                    if (jj == ii) mv[j] = -INFINITY;
                }
            }

            const double scale = 2.5 / (wsum + 1e-20);
            if (valid && l < 8) {
                out_idx[t * 8 + l] = (float)my_ii;
                out_w[t * 8 + l]   = (float)(my_w * scale);
            }
        }
        __syncthreads();
    }
}

// ---------------------------------------------------------------------------
extern "C" void kernel_launch(void* const* d_in, const int* in_sizes, int n_in,
                              void* d_out, int out_size, void* d_ws, size_t ws_size,
                              hipStream_t stream)
{
    const float* x    = (const float*)d_in[0];
    const float* w    = (const float*)d_in[1];
    const float* bias = (const float*)d_in[2];
    float* out = (float*)d_out;

    // workspace layout
    int*    cnt  = (int*)d_ws;                          // [0,256)
    int*    list = (int*)((char*)d_ws + 256);           // 64 KB
    bf16_t* whi  = (bf16_t*)((char*)d_ws + 66048);      // 3,670,016 B
    bf16_t* wlo  = (bf16_t*)((char*)d_ws + 66048 + 3670016);
    double* part = (double*)((char*)d_ws + 7406080);

    size_t avail = (ws_size > 7406080) ? (ws_size - 7406080) : 0;
    long cap_l = (long)(avail / ((size_t)KSEG * NEXP * 8));   // 16 KB per slot
    int CAP = (int)(cap_l > 4096 ? 4096 : cap_l);

    hipMemsetAsync(d_ws, 0, 4, stream);
    prep_w<<<896, 256, 0, stream>>>(w, whi, wlo);
    gate_mfma<<<256, 256, 0, stream>>>(x, whi, wlo, bias, out, cnt, list);
    if (CAP > 0) {
        for (int p = 0; p < 2; ++p) {
            repair_partial<<<dim3(128, KSEG), 256, 0, stream>>>(x, w, list, cnt, part, p * CAP, CAP);
            repair_gate<<<64, 256, 0, stream>>>(bias, list, cnt, part, out, p * CAP, CAP);
        }
    }
}

// Round 5
// 470.157 us; speedup vs baseline: 4.5197x; 1.8058x over previous
//
#include <hip/hip_runtime.h>
#include <math.h>

// MoE gate: bf16x3 split MFMA GEMM (fragment-linear LDS, global_load_lds,
// 8 waves/block) + fp32 gating with margin flags + exact fp64 repair.
// T=16384, H=7168, E=256, 8 groups, top4 groups, top8 experts.
// Output (float*): [0..T*8) = topk_idx as float, [T*8..2*T*8) = topk_weight.

typedef __bf16 bf16_t;
typedef __bf16 bf16x4 __attribute__((ext_vector_type(4)));
typedef __bf16 bf16x8 __attribute__((ext_vector_type(8)));
typedef float  f32x4  __attribute__((ext_vector_type(4)));

constexpr int T_TOT = 16384;
constexpr int HID   = 7168;
constexpr int NEXP  = 256;

constexpr int BM1  = 64;
constexpr int BK1  = 32;
constexpr int NCH1 = HID / BK1;   // 224

// LDS layout (dynamic, 81920 B):
//  [0, 32768)        B buf0: hi 16K | lo 16K   (16 frags x 1KB each)
//  [32768, 65536)    B buf1
//  [65536, 73728)    A buf0: hi 4K | lo 4K     (4 frags x 1KB)
//  [73728, 81920)    A buf1
//  epilogue alias:   logits f32 [64][264]
constexpr int B_BUF_SZ = 32768;
constexpr int A_OFF    = 65536;
constexpr int A_BUF_SZ = 8192;
constexpr int SMEM_SZ  = 81920;
constexpr int LSTR     = 264;

// margin thresholds (score scale); bf16x3 score err 6sigma ~1.2e-5 -> ~20x.
constexpr float ETHR = 5e-5f;
constexpr float GTHR = 1e-4f;

constexpr int LISTCAP = 16384;
constexpr int KSEG = 8;
constexpr int SEGK = HID / KSEG;  // 896
constexpr int TB2  = 8;

// ---------------------------------------------------------------------------
__device__ __forceinline__ void async16(const void* g, void* l)
{
    auto* lds = reinterpret_cast<__attribute__((address_space(3))) unsigned int*>(
        reinterpret_cast<uintptr_t>(l));
    const auto* gl = reinterpret_cast<const __attribute__((address_space(1))) unsigned int*>(
        reinterpret_cast<uintptr_t>(g));
    __builtin_amdgcn_global_load_lds(gl, lds, 16, 0, 0);
}

// ---------------------------------------------------------------------------
// Kernel 0: pack W fp32 -> bf16 hi/lo in MFMA-fragment order:
//   wpk[c][f][s][8] : e = f*16 + (s&15), k = c*32 + (s>>4)*8 + j
// ---------------------------------------------------------------------------
__global__ __launch_bounds__(256)
void prep_w(const float* __restrict__ w, bf16_t* __restrict__ whi,
            bf16_t* __restrict__ wlo)
{
    const int gid = blockIdx.x * 256 + threadIdx.x;   // 229376
    const int c = gid >> 10;
    const int r = gid & 1023;
    const int f = r >> 6;
    const int s = r & 63;
    const int e  = f * 16 + (s & 15);
    const int k0 = c * 32 + (s >> 4) * 8;

    float4 f0 = *(const float4*)(w + (long)e * HID + k0);
    float4 f1 = *(const float4*)(w + (long)e * HID + k0 + 4);
    float fv[8] = {f0.x, f0.y, f0.z, f0.w, f1.x, f1.y, f1.z, f1.w};
    bf16x8 hv, lv;
#pragma unroll
    for (int j = 0; j < 8; ++j) {
        bf16_t h = (bf16_t)fv[j];
        hv[j] = h;
        lv[j] = (bf16_t)(fv[j] - (float)h);
    }
    *(bf16x8*)(whi + (long)gid * 8) = hv;   // fully coalesced
    *(bf16x8*)(wlo + (long)gid * 8) = lv;
}

// ---------------------------------------------------------------------------
__device__ __forceinline__ void stage_B(int c, char* bbuf,
                                        const bf16_t* whi_p, const bf16_t* wlo_p,
                                        int wid, int lane)
{
    const int f0 = wid * 2;                               // wave stages frags f0, f0+1
    const long base = (((long)c * 16 + f0) * 64 + lane) * 8;
    const bf16_t* sh = whi_p + base;
    const bf16_t* sl = wlo_p + base;
    char* dh = bbuf + f0 * 1024;
    char* dl = bbuf + 16384 + f0 * 1024;
    async16(sh,       dh);
    async16(sh + 512, dh + 1024);
    async16(sl,       dl);
    async16(sl + 512, dl + 1024);
}

__device__ __forceinline__ void stage_A(float4 v, char* abuf, int unit, int half8)
{
    bf16_t h0 = (bf16_t)v.x, h1 = (bf16_t)v.y, h2 = (bf16_t)v.z, h3 = (bf16_t)v.w;
    bf16x4 h = {h0, h1, h2, h3};
    bf16x4 l = {(bf16_t)(v.x - (float)h0), (bf16_t)(v.y - (float)h1),
                (bf16_t)(v.z - (float)h2), (bf16_t)(v.w - (float)h3)};
    *(bf16x4*)(abuf + unit * 16 + half8) = h;
    *(bf16x4*)(abuf + 4096 + unit * 16 + half8) = l;
}

__device__ __forceinline__ void compute_chunk(char* smem, int buf,
                                              int mw, int nw, int lane,
                                              f32x4 acc[2][4])
{
    const char* aB = smem + A_OFF + buf * A_BUF_SZ;
    const char* bB = smem + buf * B_BUF_SZ;
    bf16x8 ah[2], al[2], bh[4], bl[4];
#pragma unroll
    for (int mi = 0; mi < 2; ++mi) {
        ah[mi] = *(const bf16x8*)(aB + (mw * 2 + mi) * 1024 + lane * 16);
        al[mi] = *(const bf16x8*)(aB + 4096 + (mw * 2 + mi) * 1024 + lane * 16);
    }
#pragma unroll
    for (int ni = 0; ni < 4; ++ni) {
        bh[ni] = *(const bf16x8*)(bB + (nw * 4 + ni) * 1024 + lane * 16);
        bl[ni] = *(const bf16x8*)(bB + 16384 + (nw * 4 + ni) * 1024 + lane * 16);
    }
    __builtin_amdgcn_s_setprio(1);
#pragma unroll
    for (int mi = 0; mi < 2; ++mi)
#pragma unroll
        for (int ni = 0; ni < 4; ++ni)
            acc[mi][ni] = __builtin_amdgcn_mfma_f32_16x16x32_bf16(ah[mi], bh[ni], acc[mi][ni], 0, 0, 0);
#pragma unroll
    for (int mi = 0; mi < 2; ++mi)
#pragma unroll
        for (int ni = 0; ni < 4; ++ni)
            acc[mi][ni] = __builtin_amdgcn_mfma_f32_16x16x32_bf16(ah[mi], bl[ni], acc[mi][ni], 0, 0, 0);
#pragma unroll
    for (int mi = 0; mi < 2; ++mi)
#pragma unroll
        for (int ni = 0; ni < 4; ++ni)
            acc[mi][ni] = __builtin_amdgcn_mfma_f32_16x16x32_bf16(al[mi], bh[ni], acc[mi][ni], 0, 0, 0);
    __builtin_amdgcn_s_setprio(0);
}

// ---------------------------------------------------------------------------
// Kernel 1: MFMA gate + flags. 256 blocks x 512 threads (8 waves, 2x4).
// ---------------------------------------------------------------------------
__global__ __launch_bounds__(512, 2)
void gate_mfma(const float* __restrict__ x, const bf16_t* __restrict__ whi_p,
               const bf16_t* __restrict__ wlo_p, const float* __restrict__ bias,
               float* __restrict__ out, int* __restrict__ cnt,
               int* __restrict__ list)
{
    extern __shared__ __align__(16) char smem[];

    const int tid = threadIdx.x;
    const int bid = blockIdx.x;
    const int swz = (bid & 7) * 32 + (bid >> 3);   // XCD swizzle, 256%8==0
    const long trow0 = (long)swz * BM1;

    const int lane = tid & 63;
    const int wid  = tid >> 6;
    const int mw = wid >> 2;      // 0..1 (32 tokens each)
    const int nw = wid & 3;       // 0..3 (64 experts each)

    // A staging map: thread -> (token, k-quad)
    const int sm = tid >> 3;                       // 0..63
    const int sq = tid & 7;                        // k = sq*4
    const int unit  = (sm >> 4) * 64 + ((sq >> 1) << 4) + (sm & 15);
    const int half8 = (sq & 1) * 8;
    const float* xrow = x + (trow0 + sm) * (long)HID + sq * 4;

    f32x4 acc[2][4] = {};

    // ---- prologue: chunk 0 -> buf0; x prefetch for chunks 1,2 ----
    stage_B(0, smem, whi_p, wlo_p, wid, lane);
    stage_A(*(const float4*)(xrow), smem + A_OFF, unit, half8);
    float4 xrA = *(const float4*)(xrow + BK1);
    float4 xrB = *(const float4*)(xrow + 2 * BK1);
    __syncthreads();

    for (int c = 0; c < NCH1; c += 2) {
        {   // chunk c (buf0); stage c+1 -> buf1
            stage_B(c + 1, smem + B_BUF_SZ, whi_p, wlo_p, wid, lane);
            stage_A(xrA, smem + A_OFF + A_BUF_SZ, unit, half8);
            if (c + 3 < NCH1) xrA = *(const float4*)(xrow + (c + 3) * BK1);
            compute_chunk(smem, 0, mw, nw, lane, acc);
            __syncthreads();
        }
        {   // chunk c+1 (buf1); stage c+2 -> buf0
            if (c + 2 < NCH1) {
                stage_B(c + 2, smem, whi_p, wlo_p, wid, lane);
                stage_A(xrB, smem + A_OFF, unit, half8);
            }
            if (c + 4 < NCH1) xrB = *(const float4*)(xrow + (c + 4) * BK1);
            compute_chunk(smem, 1, mw, nw, lane, acc);
            __syncthreads();
        }
    }

    // ---- epilogue: logits -> LDS ----
    float* lgl = (float*)smem;
#pragma unroll
    for (int mi = 0; mi < 2; ++mi)
#pragma unroll
        for (int ni = 0; ni < 4; ++ni)
#pragma unroll
            for (int r = 0; r < 4; ++r)
                lgl[(mw * 32 + mi * 16 + (lane >> 4) * 4 + r) * LSTR +
                    nw * 64 + ni * 16 + (lane & 15)] = acc[mi][ni][r];
    __syncthreads();

    // ---- gating (proven fp32) + margin flags; half-wave = 4 tokens ----
    const int l     = tid & 31;
    const int hbase = lane & 32;
    const int myGLo = l >> 3;
    const int m0    = (tid >> 5) * 4;   // 16 half-waves x 4 tokens

    float bb[8];
    {
        float4 b0 = *(const float4*)&bias[4 * l];
        float4 b1 = *(const float4*)&bias[4 * l + 128];
        bb[0] = b0.x; bb[1] = b0.y; bb[2] = b0.z; bb[3] = b0.w;
        bb[4] = b1.x; bb[5] = b1.y; bb[6] = b1.z; bb[7] = b1.w;
    }

    float* out_idx = out;
    float* out_w   = out + (long)T_TOT * 8;

    for (int i = 0; i < 4; ++i) {
        const long t = trow0 + m0 + i;
        float4 lg0 = *(const float4*)&lgl[(m0 + i) * LSTR + 4 * l];
        float4 lg1 = *(const float4*)&lgl[(m0 + i) * LSTR + 128 + 4 * l];
        float lgv[8] = {lg0.x, lg0.y, lg0.z, lg0.w, lg1.x, lg1.y, lg1.z, lg1.w};
        float sc[8], cs[8];
#pragma unroll
        for (int j = 0; j < 8; ++j) {
            sc[j] = 1.0f / (1.0f + expf(-lgv[j]));
            cs[j] = sc[j] + bb[j];
        }
        float l1, l2, h1, h2;
        {
            l1 = fmaxf(cs[0], cs[1]); l2 = fminf(cs[0], cs[1]);
            float n1 = fmaxf(l1, cs[2]); float n2 = fmaxf(fminf(l1, cs[2]), l2); l1 = n1; l2 = n2;
            n1 = fmaxf(l1, cs[3]); n2 = fmaxf(fminf(l1, cs[3]), l2); l1 = n1; l2 = n2;
            h1 = fmaxf(cs[4], cs[5]); h2 = fminf(cs[4], cs[5]);
            n1 = fmaxf(h1, cs[6]); n2 = fmaxf(fminf(h1, cs[6]), h2); h1 = n1; h2 = n2;
            n1 = fmaxf(h1, cs[7]); n2 = fmaxf(fminf(h1, cs[7]), h2); h1 = n1; h2 = n2;
        }
#pragma unroll
        for (int d = 1; d < 8; d <<= 1) {
            float o1 = __shfl_xor(l1, d), o2 = __shfl_xor(l2, d);
            float n1 = fmaxf(l1, o1);
            float n2 = fmaxf(fminf(l1, o1), fmaxf(l2, o2));
            l1 = n1; l2 = n2;
            o1 = __shfl_xor(h1, d); o2 = __shfl_xor(h2, d);
            n1 = fmaxf(h1, o1);
            n2 = fmaxf(fminf(h1, o1), fmaxf(h2, o2));
            h1 = n1; h2 = n2;
        }
        const float gLo = l1 + l2;
        const float gHi = h1 + h2;

        int rLo = 0, rHi = 0;
#pragma unroll
        for (int g = 0; g < 8; ++g) {
            float v = (g < 4) ? __shfl(gLo, hbase + g * 8)
                              : __shfl(gHi, hbase + (g - 4) * 8);
            rLo += (v > gLo || (v == gLo && g < myGLo)) ? 1 : 0;
            rHi += (v > gHi || (v == gHi && g < myGLo + 4)) ? 1 : 0;
        }
        const bool selLo = (rLo < 4);
        const bool selHi = (rHi < 4);

        float selMin =  INFINITY, unsMax = -INFINITY;
        if (selLo) selMin = gLo; else unsMax = gLo;
        if (selHi) selMin = fminf(selMin, gHi); else unsMax = fmaxf(unsMax, gHi);
#pragma unroll
        for (int d = 1; d < 32; d <<= 1) {
            selMin = fminf(selMin, __shfl_xor(selMin, d));
            unsMax = fmaxf(unsMax, __shfl_xor(unsMax, d));
        }
        const float ggap = selMin - unsMax;

        float mv[8];
#pragma unroll
        for (int j = 0; j < 8; ++j)
            mv[j] = ((j < 4) ? selLo : selHi) ? cs[j] : -INFINITY;

        float wsum = 0.0f, my_w = 0.0f;
        int my_ii = 0;
        float prevv = 0.0f, mingap = INFINITY;
#pragma unroll
        for (int k = 0; k < 9; ++k) {
            float bv = mv[0]; int bj = 0;
            if (mv[1] > bv) { bv = mv[1]; bj = 1; }
            if (mv[2] > bv) { bv = mv[2]; bj = 2; }
            if (mv[3] > bv) { bv = mv[3]; bj = 3; }
            if (mv[4] > bv) { bv = mv[4]; bj = 4; }
            if (mv[5] > bv) { bv = mv[5]; bj = 5; }
            if (mv[6] > bv) { bv = mv[6]; bj = 6; }
            if (mv[7] > bv) { bv = mv[7]; bj = 7; }
            float v = bv;
            int ii = (bj < 4) ? (4 * l + bj) : (128 + 4 * l + (bj - 4));
#pragma unroll
            for (int d = 1; d < 32; d <<= 1) {
                float ov = __shfl_xor(v, d);
                int   oi = __shfl_xor(ii, d);
                if (ov > v || (ov == v && oi < ii)) { v = ov; ii = oi; }
            }
            if (k) mingap = fminf(mingap, prevv - v);
            prevv = v;
            if (k < 8) {
                const int hi8 = ii >> 7;
                const int oj  = (ii & 3) + 4 * hi8;
                const int ol  = (ii & 127) >> 2;
                float ssel = (oj == 0) ? sc[0] : (oj == 1) ? sc[1] : (oj == 2) ? sc[2] :
                             (oj == 3) ? sc[3] : (oj == 4) ? sc[4] : (oj == 5) ? sc[5] :
                             (oj == 6) ? sc[6] : sc[7];
                float su = __shfl(ssel, hbase + ol);
                wsum += su;
                if (l == k) { my_ii = ii; my_w = su; }
#pragma unroll
                for (int j = 0; j < 8; ++j) {
                    int jj = (j < 4) ? (4 * l + j) : (128 + 4 * l + (j - 4));
                    if (jj == ii) mv[j] = -INFINITY;
                }
            }
        }

        const float scale = 2.5f / (wsum + 1e-20f);
        if (l < 8) {
            out_idx[t * 8 + l] = (float)my_ii;
            out_w[t * 8 + l]   = my_w * scale;
        }
        const bool flag = (mingap < ETHR) || (ggap < GTHR);
        if (flag && l == 0) {
            int pos = atomicAdd(cnt, 1);
            if (pos < LISTCAP) list[pos] = (int)t;
        }
    }
}

// ---------------------------------------------------------------------------
// Kernel 2: fp64 partial dots for flagged tokens (K-split)
// ---------------------------------------------------------------------------
__global__ __launch_bounds__(256)
void repair_partial(const float* __restrict__ x, const float* __restrict__ w,
                    const int* __restrict__ list, const int* __restrict__ cntp,
                    double* __restrict__ part, int base, int cap)
{
    __shared__ __align__(16) float xls[TB2 * SEGK];
    __shared__ int tokls[TB2];
    const int tid = threadIdx.x;
    const int ks  = blockIdx.y;

    int cnt = *cntp;
    if (cnt > 2 * cap)  cnt = 2 * cap;
    if (cnt > LISTCAP)  cnt = LISTCAP;
    const int cEnd = min(cnt, base + cap);

    for (int s0 = base + blockIdx.x * TB2; s0 < cEnd; s0 += gridDim.x * TB2) {
        if (tid < TB2) {
            int slot = s0 + tid;
            tokls[tid] = (slot < cEnd) ? list[slot] : 0;
        }
        __syncthreads();
        for (int q = tid; q < TB2 * (SEGK / 4); q += 256) {
            int i = q / (SEGK / 4), f = q % (SEGK / 4);
            float4 v = *(const float4*)(x + (long)tokls[i] * HID + ks * SEGK + f * 4);
            *(float4*)&xls[i * SEGK + f * 4] = v;
        }
        __syncthreads();

        double acc[TB2];
#pragma unroll
        for (int i = 0; i < TB2; ++i) acc[i] = 0.0;

        const float4* wp = (const float4*)(w + (long)tid * HID + ks * SEGK);
        for (int kb = 0; kb < SEGK / 4; ++kb) {
            float4 wv = wp[kb];
            double w0 = wv.x, w1 = wv.y, w2 = wv.z, w3 = wv.w;
#pragma unroll
            for (int i = 0; i < TB2; ++i) {
                float4 xv = *(const float4*)&xls[i * SEGK + kb * 4];
                acc[i] = fma((double)xv.x, w0, acc[i]);
                acc[i] = fma((double)xv.y, w1, acc[i]);
                acc[i] = fma((double)xv.z, w2, acc[i]);
                acc[i] = fma((double)xv.w, w3, acc[i]);
            }
        }
#pragma unroll
        for (int i = 0; i < TB2; ++i) {
            long pofs = (((long)(s0 - base) + i) * KSEG + ks) * NEXP + tid;
            part[pofs] = acc[i];
        }
        __syncthreads();
    }
}

// ---------------------------------------------------------------------------
// Kernel 3: reduce partials + exact fp64 gating for flagged tokens
// ---------------------------------------------------------------------------
__global__ __launch_bounds__(256)
void repair_gate(const float* __restrict__ bias, const int* __restrict__ list,
                 const int* __restrict__ cntp, const double* __restrict__ part,
                 float* __restrict__ out, int base, int cap)
{
    __shared__ double lgl[TB2 * NEXP];
    __shared__ int tokls[TB2];
    const int tid = threadIdx.x;

    int cnt = *cntp;
    if (cnt > 2 * cap)  cnt = 2 * cap;
    if (cnt > LISTCAP)  cnt = LISTCAP;
    const int cEnd = min(cnt, base + cap);

    float* out_idx = out;
    float* out_w   = out + (long)T_TOT * 8;

    const int l     = tid & 31;
    const int lane  = tid & 63;
    const int hbase = lane & 32;
    const int hw    = tid >> 5;
    const int myGLo = l >> 3;

    double bb[8];
    {
        float4 b0 = *(const float4*)&bias[4 * l];
        float4 b1 = *(const float4*)&bias[4 * l + 128];
        bb[0] = b0.x; bb[1] = b0.y; bb[2] = b0.z; bb[3] = b0.w;
        bb[4] = b1.x; bb[5] = b1.y; bb[6] = b1.z; bb[7] = b1.w;
    }

    for (int s0 = base + blockIdx.x * TB2; s0 < cEnd; s0 += gridDim.x * TB2) {
        if (tid < TB2) {
            int slot = s0 + tid;
            tokls[tid] = (slot < cEnd) ? list[slot] : 0;
        }
#pragma unroll
        for (int i = 0; i < TB2; ++i) {
            long pbase = (((long)(s0 - base) + i) * KSEG) * NEXP + tid;
            double s = 0.0;
#pragma unroll
            for (int ks = 0; ks < KSEG; ++ks) s += part[pbase + ks * NEXP];
            lgl[i * NEXP + tid] = s;
        }
        __syncthreads();
        {
            const int slot = s0 + hw;
            const bool valid = (slot < cEnd);
            const long t = tokls[hw];

            double sc[8], cs[8];
#pragma unroll
            for (int j = 0; j < 4; ++j) {
                double lg = lgl[hw * NEXP + 4 * l + j];
                sc[j] = 1.0 / (1.0 + exp(-lg));
                cs[j] = sc[j] + bb[j];
            }
#pragma unroll
            for (int j = 4; j < 8; ++j) {
                double lg = lgl[hw * NEXP + 128 + 4 * l + (j - 4)];
                sc[j] = 1.0 / (1.0 + exp(-lg));
                cs[j] = sc[j] + bb[j];
            }

            double l1, l2, h1, h2;
            {
                l1 = fmax(cs[0], cs[1]); l2 = fmin(cs[0], cs[1]);
                double n1 = fmax(l1, cs[2]); double n2 = fmax(fmin(l1, cs[2]), l2); l1 = n1; l2 = n2;
                n1 = fmax(l1, cs[3]); n2 = fmax(fmin(l1, cs[3]), l2); l1 = n1; l2 = n2;
                h1 = fmax(cs[4], cs[5]); h2 = fmin(cs[4], cs[5]);
                n1 = fmax(h1, cs[6]); n2 = fmax(fmin(h1, cs[6]), h2); h1 = n1; h2 = n2;
                n1 = fmax(h1, cs[7]); n2 = fmax(fmin(h1, cs[7]), h2); h1 = n1; h2 = n2;
            }
#pragma unroll
            for (int d = 1; d < 8; d <<= 1) {
                double o1 = __shfl_xor(l1, d), o2 = __shfl_xor(l2, d);
                double n1 = fmax(l1, o1);
                double n2 = fmax(fmin(l1, o1), fmax(l2, o2));
                l1 = n1; l2 = n2;
                o1 = __shfl_xor(h1, d); o2 = __shfl_xor(h2, d);
                n1 = fmax(h1, o1);
                n2 = fmax(fmin(h1, o1), fmax(h2, o2));
                h1 = n1; h2 = n2;
            }
            const double gLo = l1 + l2;
            const double gHi = h1 + h2;

            int rLo = 0, rHi = 0;
#pragma unroll
            for (int g = 0; g < 8; ++g) {
                double v = (g < 4) ? __shfl(gLo, hbase + g * 8)
                                   : __shfl(gHi, hbase + (g - 4) * 8);
                rLo += (v > gLo || (v == gLo && g < myGLo)) ? 1 : 0;
                rHi += (v > gHi || (v == gHi && g < myGLo + 4)) ? 1 : 0;
            }
            const bool selLo = (rLo < 4);
            const bool selHi = (rHi < 4);

            double mv[8];
#pragma unroll
            for (int j = 0; j < 8; ++j)
                mv[j] = ((j < 4) ? selLo : selHi) ? cs[j] : -INFINITY;

            double wsum = 0.0, my_w = 0.0;
            int my_ii = 0;
#pragma unroll
            for (int k = 0; k < 8; ++k) {
                double bv = mv[0]; int bj = 0;
                if (mv[1] > bv) { bv = mv[1]; bj = 1; }
                if (mv[2] > bv) { bv = mv[2]; bj = 2; }
                if (mv[3] > bv) { bv = mv[3]; bj = 3; }
                if (mv[4] > bv) { bv = mv[4]; bj = 4; }
                if (mv[5] > bv) { bv = mv[5]; bj = 5; }
                if (mv[6] > bv) { bv = mv[6]; bj = 6; }
                if (mv[7] > bv) { bv = mv[7]; bj = 7; }
                double v = bv;
                int ii = (bj < 4) ? (4 * l + bj) : (128 + 4 * l + (bj - 4));
#pragma unroll
                for (int d = 1; d < 32; d <<= 1) {
                    double ov = __shfl_xor(v, d);
                    int    oi = __shfl_xor(ii, d);
                    if (ov > v || (ov == v && oi < ii)) { v = ov; ii = oi; }
                }
                const int hi8 = ii >> 7;
                const int oj  = (ii & 3) + 4 * hi8;
                const int ol  = (ii & 127) >> 2;
                double ssel = (oj == 0) ? sc[0] : (oj == 1) ? sc[1] : (oj == 2) ? sc[2] :
                              (oj == 3) ? sc[3] : (oj == 4) ? sc[4] : (oj == 5) ? sc[5] :
                              (oj == 6) ? sc[6] : sc[7];
                double su = __shfl(ssel, hbase + ol);
                wsum += su;
                if (l == k) { my_ii = ii; my_w = su; }
#pragma unroll
                for (int j = 0; j < 8; ++j) {
                    int jj = (j < 4) ? (4 * l + j) : (128 + 4 * l + (j - 4));
                    if (jj == ii) mv[j] = -INFINITY;
                }
            }

            const double scale = 2.5 / (wsum + 1e-20);
            if (valid && l < 8) {
                out_idx[t * 8 + l] = (float)my_ii;
                out_w[t * 8 + l]   = (float)(my_w * scale);
            }
        }
        __syncthreads();
    }
}

// ---------------------------------------------------------------------------
extern "C" void kernel_launch(void* const* d_in, const int* in_sizes, int n_in,
                              void* d_out, int out_size, void* d_ws, size_t ws_size,
                              hipStream_t stream)
{
    const float* x    = (const float*)d_in[0];
    const float* w    = (const float*)d_in[1];
    const float* bias = (const float*)d_in[2];
    float* out = (float*)d_out;

    int*    cnt  = (int*)d_ws;                          // [0,256)
    int*    list = (int*)((char*)d_ws + 256);           // 64 KB
    bf16_t* whi  = (bf16_t*)((char*)d_ws + 66048);      // 3,670,016 B
    bf16_t* wlo  = (bf16_t*)((char*)d_ws + 66048 + 3670016);
    double* part = (double*)((char*)d_ws + 7406080);

    size_t avail = (ws_size > 7406080) ? (ws_size - 7406080) : 0;
    long cap_l = (long)(avail / ((size_t)KSEG * NEXP * 8));   // 16 KB per slot
    int CAP = (int)(cap_l > 4096 ? 4096 : cap_l);

    hipMemsetAsync(d_ws, 0, 4, stream);
    prep_w<<<896, 256, 0, stream>>>(w, whi, wlo);
    gate_mfma<<<256, 512, SMEM_SZ, stream>>>(x, whi, wlo, bias, out, cnt, list);
    if (CAP > 0) {
        for (int p = 0; p < 2; ++p) {
            repair_partial<<<dim3(128, KSEG), 256, 0, stream>>>(x, w, list, cnt, part, p * CAP, CAP);
            repair_gate<<<64, 256, 0, stream>>>(bias, list, cnt, part, out, p * CAP, CAP);
        }
    }
}